// Round 8
// baseline (1813.754 us; speedup 1.0000x reference)
//
#include <hip/hip_runtime.h>
#include <cstdint>
#include <cstddef>

#define Hh 64
#define Vv 32000
#define Bb 32
#define Tt 512

typedef _Float16 half2_t __attribute__((ext_vector_type(2)));

// ---- ws layout (bytes) ----
#define IP_OFF    0ull
#define IP_SZ     ((size_t)Bb*Tt*Hh*4)          // 4 MB   ip[b][t][j]
#define SL_OFF    (IP_OFF + IP_SZ)
#define SL_SZ     ((size_t)Bb*Tt*4)             // 64 KB  L[b][s]
#define U511_OFF  (SL_OFF + SL_SZ)
#define U511_SZ   ((size_t)Bb*Hh*Hh*4)          // 512 KB W511[b][j][i] f32
#define STAGE_OFF (U511_OFF + U511_SZ)
#define STAGE_SZ  ((size_t)Tt*Bb*Hh*Hh*2)       // 128 MB stage[s][b][j][i] bf16

__device__ __forceinline__ float wave_max64(float v){
  #pragma unroll
  for (int off=32; off; off>>=1) v = fmaxf(v, __shfl_xor(v, off, 64));
  return v;
}

__device__ __forceinline__ half2_t pk16(float x, float y){
  return __builtin_bit_cast(half2_t, __builtin_amdgcn_cvt_pkrtz(x, y));
}

// zbuf: 64 rows x 128B (64 f16), 16B chunks placed at (chunk ^ key(row)),
// key(row) = ((row>>3) ^ row) & 7.  Byte offset of (row, chunk):
__device__ __forceinline__ int zaddr(int row, int chunk){
  int key = ((row >> 3) ^ row) & 7;
  return row*128 + ((chunk ^ key) << 4);
}

// emissions: ip[b][t][j] = beta[j][ids[b][t]]   (grid 32*128, block 256)
__global__ __launch_bounds__(256) void sohmm_ipfill(
    const float* __restrict__ beta, const int* __restrict__ ids,
    float* __restrict__ ipbuf)
{
  const int bid = blockIdx.x;
  const int b = bid >> 7, tq = bid & 127;
  const int t = tq*4 + (threadIdx.x >> 6);
  const int j = threadIdx.x & 63;
  const int id = ids[b*Tt + t];
  ipbuf[((size_t)b*Tt + t)*Hh + j] = beta[(size_t)j*Vv + id];
}

// One WG (256 threads, 4 waves, 1 wave/SIMD) per chain.
// thread (j = tid>>2, igrp = tid&3) owns outputs (i = igrp*16+m, j), m=0..15.
// alpha f16: rows m=0..12 in registers, rows 13..15 in LDS (private, swizzled).
__global__ __launch_bounds__(256, 1) void sohmm_scan(
    const float* __restrict__ alpha, const float* __restrict__ ipbuf,
    float* __restrict__ out, float* __restrict__ SL,
    float* __restrict__ u511, unsigned int* __restrict__ stage, int use_stage)
{
  const int b    = blockIdx.x;
  const int tid  = threadIdx.x;
  const int j    = tid >> 2;     // 0..63
  const int igrp = tid & 3;      // 0..3
  const int w    = tid >> 6;     // wave 0..3
  const int lane = tid & 63;
  const int swz  = tid & 7;

  __shared__ char zb[2][64*128];        // 16,384 B  state V f16, swizzled chunks
  __shared__ char aL[256*384];          // 98,304 B  3 alpha rows per thread, swizzled
  __shared__ float wred[2][4];

  // ---- alpha rows 0..12 -> registers (f16) ----
  half2_t areg[13][32];
  #pragma unroll
  for (int m=0; m<13; m++){
    const float4* ap = (const float4*)(alpha + (((size_t)(igrp*16+m))*Hh + j)*Hh);
    #pragma unroll
    for (int q=0; q<16; q++){
      float4 v = ap[q];
      areg[m][2*q+0] = pk16(v.x, v.y);
      areg[m][2*q+1] = pk16(v.z, v.w);
    }
  }
  // ---- alpha rows 13..15 -> LDS, 16B chunks at (cc ^ swz) ----
  #pragma unroll
  for (int mm=0; mm<3; mm++){
    const float4* ap = (const float4*)(alpha + (((size_t)(igrp*16+13+mm))*Hh + j)*Hh);
    #pragma unroll
    for (int cc=0; cc<8; cc++){
      float4 v0 = ap[2*cc], v1 = ap[2*cc+1];
      uint4 u;
      u.x = __builtin_bit_cast(unsigned, __builtin_amdgcn_cvt_pkrtz(v0.x, v0.y));
      u.y = __builtin_bit_cast(unsigned, __builtin_amdgcn_cvt_pkrtz(v0.z, v0.w));
      u.z = __builtin_bit_cast(unsigned, __builtin_amdgcn_cvt_pkrtz(v1.x, v1.y));
      u.w = __builtin_bit_cast(unsigned, __builtin_amdgcn_cvt_pkrtz(v1.z, v1.w));
      *(uint4*)(aL + (size_t)tid*384 + mm*128 + ((cc ^ swz) << 4)) = u;
    }
  }
  __syncthreads();

  float L = 0.f;

  for (int s=0; s<Tt; s++){
    const int cs = s & 1, ps = cs ^ 1;
    const int t  = (Tt-1) - s;

    float ipv = ipbuf[((size_t)b*Tt + t)*Hh + j];   // issued early, used late

    float acc[16];
    #pragma unroll
    for (int m=0;m<16;m++) acc[m] = 0.f;

    if (s){
      #pragma unroll
      for (int h=0; h<2; h++){
        unsigned zz[16];
        #pragma unroll
        for (int c=0; c<4; c++){
          uint4 zq = *(const uint4*)(zb[ps] + zaddr(j, h*4 + c));
          zz[4*c+0]=zq.x; zz[4*c+1]=zq.y; zz[4*c+2]=zq.z; zz[4*c+3]=zq.w;
        }
        #pragma unroll
        for (int m=0; m<13; m++){
          #pragma unroll
          for (int p=0; p<16; p++)
            acc[m] = __builtin_amdgcn_fdot2(areg[m][16*h+p],
                       __builtin_bit_cast(half2_t, zz[p]), acc[m], false);
        }
        #pragma unroll
        for (int mm=0; mm<3; mm++){
          unsigned aa[16];
          #pragma unroll
          for (int c=0; c<4; c++){
            uint4 aq = *(const uint4*)(aL + (size_t)tid*384 + mm*128 + (((h*4+c) ^ swz) << 4));
            aa[4*c+0]=aq.x; aa[4*c+1]=aq.y; aa[4*c+2]=aq.z; aa[4*c+3]=aq.w;
          }
          #pragma unroll
          for (int p=0; p<16; p++)
            acc[13+mm] = __builtin_amdgcn_fdot2(__builtin_bit_cast(half2_t, aa[p]),
                           __builtin_bit_cast(half2_t, zz[p]), acc[13+mm], false);
        }
      }
      float e = __expf(ipv);
      #pragma unroll
      for (int m=0;m<16;m++) acc[m] *= e;       // W_s
    } else {
      float e = __expf(ipv);
      #pragma unroll
      for (int m=0;m<16;m++) acc[m] = e;        // W_0 = exp(ip), same for all i
    }

    // block max -> wred[cs]
    float vm = acc[0];
    #pragma unroll
    for (int m=1;m<16;m++) vm = fmaxf(vm, acc[m]);
    vm = wave_max64(vm);
    if (lane==0) wred[cs][w] = vm;

    // L_s = L_{s-1} + log(mu_{s-1})   (wred[ps] stable since last step's mid barrier)
    if (s) L += __logf(fmaxf(fmaxf(wred[ps][0],wred[ps][1]), fmaxf(wred[ps][2],wred[ps][3])));
    if (tid==0) SL[(size_t)b*Tt + s] = L;

    // out staging: bf16(W) (emit kernel adds L and transposes), or direct fallback
    if (use_stage){
      unsigned pk8[8];
      #pragma unroll
      for (int q=0;q<8;q++)
        pk8[q] = (__float_as_uint(acc[2*q]) >> 16) | (__float_as_uint(acc[2*q+1]) & 0xFFFF0000u);
      unsigned* dst = stage + ((size_t)s*Bb + b)*2048 + (size_t)j*32 + igrp*8;
      uint4 o0; o0.x=pk8[0]; o0.y=pk8[1]; o0.z=pk8[2]; o0.w=pk8[3];
      uint4 o1; o1.x=pk8[4]; o1.y=pk8[5]; o1.z=pk8[6]; o1.w=pk8[7];
      ((uint4*)dst)[0] = o0; ((uint4*)dst)[1] = o1;
    } else {
      #pragma unroll
      for (int m=0;m<16;m++)
        out[(((size_t)s*Hh + (igrp*16+m))*Hh + j)*Bb + b] = __logf(acc[m]) + L;
    }
    if (s == Tt-1){
      float4* ud = (float4*)(u511 + (size_t)b*4096 + (size_t)j*64 + igrp*16);
      #pragma unroll
      for (int q=0;q<4;q++){
        float4 o; o.x=acc[4*q]; o.y=acc[4*q+1]; o.z=acc[4*q+2]; o.w=acc[4*q+3];
        ud[q] = o;
      }
    }

    __syncthreads();   // wred[cs] complete

    float mu   = fmaxf(fmaxf(wred[cs][0],wred[cs][1]), fmaxf(wred[cs][2],wred[cs][3]));
    float rinv = 1.0f / mu;
    {
      const int jc = j >> 3, jo = (j & 7) * 2;
      #pragma unroll
      for (int m=0;m<16;m++){
        int i = igrp*16 + m;
        _Float16 hv = (_Float16)fmaxf(acc[m]*rinv, 1e-7f);   // clamp: no all-zero rows
        *(short*)(zb[cs] + zaddr(i, jc) + jo) = __builtin_bit_cast(short, hv);
      }
    }
    __syncthreads();   // zb[cs] ready for next step
  }
}

// transpose + log: stage[s][b][j][i] bf16 -> out[s][i][j][b] f32 (= log(W)+L)
__global__ __launch_bounds__(256) void sohmm_emit(
    const unsigned short* __restrict__ stage, const float* __restrict__ SL,
    float* __restrict__ out)
{
  const int s  = blockIdx.x >> 3;
  const int jb = blockIdx.x & 7;
  const int tid = threadIdx.x;

  __shared__ unsigned short T[32*514];
  __shared__ float Sl[32];

  if (tid < 32) Sl[tid] = SL[(size_t)tid*Tt + s];

  #pragma unroll 4
  for (int bb=0; bb<32; bb++){
    ushort2 v = ((const ushort2*)(stage + ((size_t)s*Bb + bb)*4096 + (size_t)jb*512))[tid];
    *(ushort2*)(&T[bb*514 + tid*2]) = v;
  }
  __syncthreads();

  const int bch = tid & 31;
  const int pg  = tid >> 5;
  #pragma unroll 4
  for (int r=0; r<64; r++){
    int p  = r*8 + pg;
    int jr = p >> 6;
    int i  = p & 63;
    unsigned short h = T[bch*514 + jr*64 + i];
    float u = __uint_as_float(((unsigned)h) << 16);
    out[(((size_t)s*Hh + i)*Hh + (jb*8 + jr))*Bb + bch] = __logf(u) + Sl[bch];
  }
}

__global__ __launch_bounds__(256) void sohmm_final(
    const float* __restrict__ gamma, const float* __restrict__ u511,
    const float* __restrict__ SL, float* __restrict__ out)
{
  const int b = blockIdx.x, tid = threadIdx.x;
  const int w = tid>>6, lane = tid&63;
  __shared__ float red[4], red2[4];

  float gm = -3.4e38f;
  #pragma unroll
  for (int q=0;q<16;q++) gm = fmaxf(gm, gamma[q*256+tid]);
  gm = wave_max64(gm);
  if (lane==0) red[w] = gm;
  __syncthreads();
  gm = fmaxf(fmaxf(red[0],red[1]), fmaxf(red[2],red[3]));
  __syncthreads();

  float se=0.f, dot=0.f;
  #pragma unroll
  for (int q=0;q<16;q++){
    int idx = q*256+tid;             // i*64+j
    int ii = idx>>6, jj = idx&63;
    float gq = __expf(gamma[idx]-gm);
    se  += gq;
    dot += gq * u511[(size_t)b*4096 + (size_t)jj*64 + ii];
  }
  #pragma unroll
  for (int off=32; off; off>>=1){
    se  += __shfl_xor(se,  off, 64);
    dot += __shfl_xor(dot, off, 64);
  }
  if (lane==0){ red[w]=se; red2[w]=dot; }
  __syncthreads();
  if (tid==0){
    float ses  = red[0]+red[1]+red[2]+red[3];
    float dots = red2[0]+red2[1]+red2[2]+red2[3];
    out[(size_t)Tt*Hh*Hh*Bb + b] = __logf(dots/ses) + SL[(size_t)b*Tt + (Tt-1)];
  }
}

extern "C" void kernel_launch(void* const* d_in, const int* in_sizes, int n_in,
                              void* d_out, int out_size, void* d_ws, size_t ws_size,
                              hipStream_t stream)
{
  (void)in_sizes; (void)n_in; (void)out_size;
  const float* alpha = (const float*)d_in[0];
  const float* beta  = (const float*)d_in[1];
  const float* gamma = (const float*)d_in[2];
  const int*   ids   = (const int*)d_in[3];
  float* out = (float*)d_out;
  char*  ws  = (char*)d_ws;

  float*          ipbuf = (float*)(ws + IP_OFF);
  float*          SLp   = (float*)(ws + SL_OFF);
  float*          u511p = (float*)(ws + U511_OFF);
  unsigned int*   stage = (unsigned int*)(ws + STAGE_OFF);

  const int use_stage = (ws_size >= STAGE_OFF + STAGE_SZ) ? 1 : 0;

  hipLaunchKernelGGL(sohmm_ipfill, dim3(Bb*128), dim3(256), 0, stream, beta, ids, ipbuf);
  hipLaunchKernelGGL(sohmm_scan, dim3(Bb), dim3(256), 0, stream,
                     alpha, ipbuf, out, SLp, u511p, stage, use_stage);
  if (use_stage){
    hipLaunchKernelGGL(sohmm_emit, dim3(Tt*8), dim3(256), 0, stream,
                       (const unsigned short*)stage, SLp, out);
  }
  hipLaunchKernelGGL(sohmm_final, dim3(Bb), dim3(256), 0, stream,
                     gamma, u511p, SLp, out);
}

// Round 9
// 1219.031 us; speedup vs baseline: 1.4879x; 1.4879x over previous
//
#include <hip/hip_runtime.h>
#include <cstdint>
#include <cstddef>

#define Hh 64
#define Vv 32000
#define Bb 32
#define Tt 512

typedef _Float16 half2_t __attribute__((ext_vector_type(2)));

// ---- ws layout (bytes) ----
#define IP_OFF    0ull
#define IP_SZ     ((size_t)Bb*Tt*Hh*4)          // 4 MB   ip[b][t][j]
#define SL_OFF    (IP_OFF + IP_SZ)
#define SL_SZ     ((size_t)Bb*Tt*4)             // 64 KB  L[b][s]
#define U511_OFF  (SL_OFF + SL_SZ)
#define U511_SZ   ((size_t)Bb*Hh*Hh*4)          // 512 KB W511[b][j][i] f32
#define STAGE_OFF (U511_OFF + U511_SZ)
#define STAGE_SZ  ((size_t)Tt*Bb*Hh*Hh*2)       // 128 MB stage[s][b][j][i] bf16

__device__ __forceinline__ float wave_max64(float v){
  #pragma unroll
  for (int off=32; off; off>>=1) v = fmaxf(v, __shfl_xor(v, off, 64));
  return v;
}

__device__ __forceinline__ half2_t pk16(float x, float y){
  return __builtin_bit_cast(half2_t, __builtin_amdgcn_cvt_pkrtz(x, y));
}

// emissions: ip[b][t][j] = beta[j][ids[b][t]]   (grid 32*128, block 256)
__global__ __launch_bounds__(256) void sohmm_ipfill(
    const float* __restrict__ beta, const int* __restrict__ ids,
    float* __restrict__ ipbuf)
{
  const int bid = blockIdx.x;
  const int b = bid >> 7, tq = bid & 127;
  const int t = tq*4 + (threadIdx.x >> 6);
  const int j = threadIdx.x & 63;
  const int id = ids[b*Tt + t];
  ipbuf[((size_t)b*Tt + t)*Hh + j] = beta[(size_t)j*Vv + id];
}

// One WG (512 threads, 8 waves, 2 waves/SIMD) per chain.
// thread (j = tid>>3, igrp = tid&7) owns outputs (i = igrp*8+m, j), m=0..7.
// alpha f16: rows m=0..5 in regs (192 VGPR), rows 6..7 in LDS (plain layout).
// zb state: 64 rows x 128B f16, 16B chunk c of row r at (c ^ ((r>>3)^r)&7).
__global__ __launch_bounds__(512, 2) void sohmm_scan(
    const float* __restrict__ alpha, const float* __restrict__ ipbuf,
    float* __restrict__ out, float* __restrict__ SL,
    float* __restrict__ u511, unsigned int* __restrict__ stage, int use_stage)
{
  const int b    = blockIdx.x;
  const int tid  = threadIdx.x;
  const int j    = tid >> 3;     // 0..63
  const int igrp = tid & 7;      // 0..7
  const int w    = tid >> 6;     // wave 0..7
  const int lane = tid & 63;
  const int i0   = igrp * 8;

  __shared__ char zb[2][64*128];        // 16,384 B   state V f16, swizzled chunks
  __shared__ char aL[512*272];          // 139,264 B  2 alpha rows per thread, plain
  __shared__ float wred[2][8];

  // ---- alpha rows 0..5 -> registers (f16) ----
  half2_t areg[6][32];
  #pragma unroll
  for (int m=0; m<6; m++){
    const float4* ap = (const float4*)(alpha + (((size_t)(i0+m))*Hh + j)*Hh);
    #pragma unroll
    for (int q=0; q<16; q++){
      float4 v = ap[q];
      areg[m][2*q+0] = pk16(v.x, v.y);
      areg[m][2*q+1] = pk16(v.z, v.w);
    }
  }
  // ---- alpha rows 6..7 -> LDS (private 256B block + 16B pad, imm offsets) ----
  #pragma unroll
  for (int mm=0; mm<2; mm++){
    const float4* ap = (const float4*)(alpha + (((size_t)(i0+6+mm))*Hh + j)*Hh);
    #pragma unroll
    for (int q=0; q<8; q++){
      float4 v0 = ap[2*q], v1 = ap[2*q+1];
      uint4 u;
      u.x = __builtin_bit_cast(unsigned, __builtin_amdgcn_cvt_pkrtz(v0.x, v0.y));
      u.y = __builtin_bit_cast(unsigned, __builtin_amdgcn_cvt_pkrtz(v0.z, v0.w));
      u.z = __builtin_bit_cast(unsigned, __builtin_amdgcn_cvt_pkrtz(v1.x, v1.y));
      u.w = __builtin_bit_cast(unsigned, __builtin_amdgcn_cvt_pkrtz(v1.z, v1.w));
      *(uint4*)(aL + (size_t)tid*272 + mm*128 + q*16) = u;
    }
  }
  __syncthreads();

  const int kzj = ((j >> 3) ^ j) & 7;   // read-side swizzle key (per-thread const)
  const int jc  = j >> 3;               // write-side chunk
  const int jo  = (j & 7) * 2;          // write-side byte offset in chunk

  float L = 0.f;

  for (int s=0; s<Tt; s++){
    const int cs = s & 1, ps = cs ^ 1;
    const int t  = (Tt-1) - s;

    float ipv = ipbuf[((size_t)b*Tt + t)*Hh + j];   // issued early, used late

    float acc[8];
    #pragma unroll
    for (int m=0;m<8;m++) acc[m] = 0.f;

    if (s){
      const char* zrow = zb[ps] + j*128;
      const char* arow = aL + (size_t)tid*272;
      #pragma unroll
      for (int h=0; h<2; h++){
        unsigned zz[16];
        #pragma unroll
        for (int c=0; c<4; c++){
          uint4 zq = *(const uint4*)(zrow + (((h*4+c) ^ kzj) << 4));
          zz[4*c+0]=zq.x; zz[4*c+1]=zq.y; zz[4*c+2]=zq.z; zz[4*c+3]=zq.w;
        }
        #pragma unroll
        for (int m=0; m<6; m++){
          #pragma unroll
          for (int p=0; p<16; p++)
            acc[m] = __builtin_amdgcn_fdot2(areg[m][16*h+p],
                       __builtin_bit_cast(half2_t, zz[p]), acc[m], false);
        }
        #pragma unroll
        for (int mm=0; mm<2; mm++){
          unsigned aa[16];
          #pragma unroll
          for (int c=0; c<4; c++){
            uint4 aq = *(const uint4*)(arow + mm*128 + h*64 + c*16);
            aa[4*c+0]=aq.x; aa[4*c+1]=aq.y; aa[4*c+2]=aq.z; aa[4*c+3]=aq.w;
          }
          #pragma unroll
          for (int p=0; p<16; p++)
            acc[6+mm] = __builtin_amdgcn_fdot2(__builtin_bit_cast(half2_t, aa[p]),
                           __builtin_bit_cast(half2_t, zz[p]), acc[6+mm], false);
        }
      }
      float e = __expf(ipv);
      #pragma unroll
      for (int m=0;m<8;m++) acc[m] *= e;        // W_s
    } else {
      float e = __expf(ipv);
      #pragma unroll
      for (int m=0;m<8;m++) acc[m] = e;         // W_0 = exp(ip), same for all i
    }

    // block max -> wred[cs]
    float vm = acc[0];
    #pragma unroll
    for (int m=1;m<8;m++) vm = fmaxf(vm, acc[m]);
    vm = wave_max64(vm);
    if (lane==0) wred[cs][w] = vm;

    // L_s = L_{s-1} + log(mu_{s-1})  (wred[ps] stable since prev step's 2nd barrier)
    if (s){
      float mu8 = wred[ps][0];
      #pragma unroll
      for (int q=1;q<8;q++) mu8 = fmaxf(mu8, wred[ps][q]);
      L += __logf(mu8);
    }
    if (tid==0) SL[(size_t)b*Tt + s] = L;

    // out staging: bf16(W) (emit kernel adds L and transposes), or direct fallback
    if (use_stage){
      unsigned pk4[4];
      #pragma unroll
      for (int q=0;q<4;q++)
        pk4[q] = (__float_as_uint(acc[2*q]) >> 16) | (__float_as_uint(acc[2*q+1]) & 0xFFFF0000u);
      uint4 o; o.x=pk4[0]; o.y=pk4[1]; o.z=pk4[2]; o.w=pk4[3];
      *(uint4*)(stage + ((size_t)s*Bb + b)*2048 + (size_t)j*32 + igrp*4) = o;
    } else {
      #pragma unroll
      for (int m=0;m<8;m++)
        out[(((size_t)s*Hh + (i0+m))*Hh + j)*Bb + b] = __logf(acc[m]) + L;
    }
    if (s == Tt-1){
      float4* ud = (float4*)(u511 + (size_t)b*4096 + (size_t)j*64 + i0);
      #pragma unroll
      for (int q=0;q<2;q++){
        float4 o; o.x=acc[4*q]; o.y=acc[4*q+1]; o.z=acc[4*q+2]; o.w=acc[4*q+3];
        ud[q] = o;
      }
    }

    __syncthreads();   // wred[cs] complete

    float mu   = wred[cs][0];
    #pragma unroll
    for (int q=1;q<8;q++) mu = fmaxf(mu, wred[cs][q]);
    float rinv = 1.0f / mu;
    {
      #pragma unroll
      for (int m=0;m<8;m++){
        int i = i0 + m;
        int ck = (jc ^ igrp ^ m) & 7;                         // chunk ^ key(i)
        _Float16 hv = (_Float16)fmaxf(acc[m]*rinv, 1e-7f);    // clamp: no all-zero rows
        *(short*)(zb[cs] + i*128 + (ck<<4) + jo) = __builtin_bit_cast(short, hv);
      }
    }
    __syncthreads();   // zb[cs] ready for next step
  }
}

// transpose + log: stage[s][b][j][i] bf16 -> out[s][i][j][b] f32 (= log(W)+L)
__global__ __launch_bounds__(256) void sohmm_emit(
    const unsigned short* __restrict__ stage, const float* __restrict__ SL,
    float* __restrict__ out)
{
  const int s  = blockIdx.x >> 3;
  const int jb = blockIdx.x & 7;
  const int tid = threadIdx.x;

  __shared__ unsigned short T[32*514];
  __shared__ float Sl[32];

  if (tid < 32) Sl[tid] = SL[(size_t)tid*Tt + s];

  #pragma unroll 4
  for (int bb=0; bb<32; bb++){
    ushort2 v = ((const ushort2*)(stage + ((size_t)s*Bb + bb)*4096 + (size_t)jb*512))[tid];
    *(ushort2*)(&T[bb*514 + tid*2]) = v;
  }
  __syncthreads();

  const int bch = tid & 31;
  const int pg  = tid >> 5;
  #pragma unroll 4
  for (int r=0; r<64; r++){
    int p  = r*8 + pg;
    int jr = p >> 6;
    int i  = p & 63;
    unsigned short h = T[bch*514 + jr*64 + i];
    float u = __uint_as_float(((unsigned)h) << 16);
    out[(((size_t)s*Hh + i)*Hh + (jb*8 + jr))*Bb + bch] = __logf(u) + Sl[bch];
  }
}

__global__ __launch_bounds__(256) void sohmm_final(
    const float* __restrict__ gamma, const float* __restrict__ u511,
    const float* __restrict__ SL, float* __restrict__ out)
{
  const int b = blockIdx.x, tid = threadIdx.x;
  const int w = tid>>6, lane = tid&63;
  __shared__ float red[4], red2[4];

  float gm = -3.4e38f;
  #pragma unroll
  for (int q=0;q<16;q++) gm = fmaxf(gm, gamma[q*256+tid]);
  gm = wave_max64(gm);
  if (lane==0) red[w] = gm;
  __syncthreads();
  gm = fmaxf(fmaxf(red[0],red[1]), fmaxf(red[2],red[3]));
  __syncthreads();

  float se=0.f, dot=0.f;
  #pragma unroll
  for (int q=0;q<16;q++){
    int idx = q*256+tid;             // i*64+j
    int ii = idx>>6, jj = idx&63;
    float gq = __expf(gamma[idx]-gm);
    se  += gq;
    dot += gq * u511[(size_t)b*4096 + (size_t)jj*64 + ii];
  }
  #pragma unroll
  for (int off=32; off; off>>=1){
    se  += __shfl_xor(se,  off, 64);
    dot += __shfl_xor(dot, off, 64);
  }
  if (lane==0){ red[w]=se; red2[w]=dot; }
  __syncthreads();
  if (tid==0){
    float ses  = red[0]+red[1]+red[2]+red[3];
    float dots = red2[0]+red2[1]+red2[2]+red2[3];
    out[(size_t)Tt*Hh*Hh*Bb + b] = __logf(dots/ses) + SL[(size_t)b*Tt + (Tt-1)];
  }
}

extern "C" void kernel_launch(void* const* d_in, const int* in_sizes, int n_in,
                              void* d_out, int out_size, void* d_ws, size_t ws_size,
                              hipStream_t stream)
{
  (void)in_sizes; (void)n_in; (void)out_size;
  const float* alpha = (const float*)d_in[0];
  const float* beta  = (const float*)d_in[1];
  const float* gamma = (const float*)d_in[2];
  const int*   ids   = (const int*)d_in[3];
  float* out = (float*)d_out;
  char*  ws  = (char*)d_ws;

  float*          ipbuf = (float*)(ws + IP_OFF);
  float*          SLp   = (float*)(ws + SL_OFF);
  float*          u511p = (float*)(ws + U511_OFF);
  unsigned int*   stage = (unsigned int*)(ws + STAGE_OFF);

  const int use_stage = (ws_size >= STAGE_OFF + STAGE_SZ) ? 1 : 0;

  hipLaunchKernelGGL(sohmm_ipfill, dim3(Bb*128), dim3(256), 0, stream, beta, ids, ipbuf);
  hipLaunchKernelGGL(sohmm_scan, dim3(Bb), dim3(512), 0, stream,
                     alpha, ipbuf, out, SLp, u511p, stage, use_stage);
  if (use_stage){
    hipLaunchKernelGGL(sohmm_emit, dim3(Tt*8), dim3(256), 0, stream,
                       (const unsigned short*)stage, SLp, out);
  }
  hipLaunchKernelGGL(sohmm_final, dim3(Bb), dim3(256), 0, stream,
                     gamma, u511p, SLp, out);
}

// Round 12
// 1216.563 us; speedup vs baseline: 1.4909x; 1.0020x over previous
//
#include <hip/hip_runtime.h>
#include <cstdint>
#include <cstddef>

#define Hh 64
#define Vv 32000
#define Bb 32
#define Tt 512

typedef _Float16 half2_t __attribute__((ext_vector_type(2)));

// ---- ws layout (bytes) ----
#define IP_OFF    0ull
#define IP_SZ     ((size_t)Bb*Tt*Hh*4)          // 4 MB   ip[b][t][j]
#define SL_OFF    (IP_OFF + IP_SZ)
#define SL_SZ     ((size_t)Bb*Tt*4)             // 64 KB  L[b][s]
#define U511_OFF  (SL_OFF + SL_SZ)
#define U511_SZ   ((size_t)Bb*Hh*Hh*4)          // 512 KB W511[b][j][i] f32
#define STAGE_OFF (U511_OFF + U511_SZ)
#define STAGE_SZ  ((size_t)Tt*Bb*Hh*Hh*2)       // 128 MB stage[s][b][j][i] bf16

__device__ __forceinline__ float wave_max64(float v){
  #pragma unroll
  for (int off=32; off; off>>=1) v = fmaxf(v, __shfl_xor(v, off, 64));
  return v;
}

__device__ __forceinline__ half2_t pk16(float x, float y){
  return __builtin_bit_cast(half2_t, __builtin_amdgcn_cvt_pkrtz(x, y));
}

// emissions: ip[b][t][j] = beta[j][ids[b][t]]   (grid 32*128, block 256)
__global__ __launch_bounds__(256) void sohmm_ipfill(
    const float* __restrict__ beta, const int* __restrict__ ids,
    float* __restrict__ ipbuf)
{
  const int bid = blockIdx.x;
  const int b = bid >> 7, tq = bid & 127;
  const int t = tq*4 + (threadIdx.x >> 6);
  const int j = threadIdx.x & 63;
  const int id = ids[b*Tt + t];
  ipbuf[((size_t)b*Tt + t)*Hh + j] = beta[(size_t)j*Vv + id];
}

// One WG (512 threads, 8 waves, EXACTLY 2 waves/SIMD -> 256 VGPR/wave) per chain.
// thread (j = tid>>3, igrp = tid&7) owns outputs (i = igrp*8+m, j), m=0..7.
// alpha f16: rows m=0..5 in regs (192 VGPR), rows 6..7 in LDS (plain layout).
// zb state: 64 rows x 128B f16, 16B chunk c of row r at (c ^ ((r>>3)^r)&7).
__global__ __launch_bounds__(512)
__attribute__((amdgpu_waves_per_eu(2, 2)))
void sohmm_scan(
    const float* __restrict__ alpha, const float* __restrict__ ipbuf,
    float* __restrict__ out, float* __restrict__ SL,
    float* __restrict__ u511, unsigned int* __restrict__ stage, int use_stage)
{
  const int b    = blockIdx.x;
  const int tid  = threadIdx.x;
  const int j    = tid >> 3;     // 0..63
  const int igrp = tid & 7;      // 0..7
  const int w    = tid >> 6;     // wave 0..7
  const int lane = tid & 63;
  const int i0   = igrp * 8;

  __shared__ char zb[2][64*128];        // 16,384 B   state V f16, swizzled chunks
  __shared__ char aL[512*272];          // 139,264 B  2 alpha rows per thread, plain
  __shared__ float wred[2][8];

  // ---- alpha rows 0..5 -> registers (f16) ----
  half2_t areg[6][32];
  #pragma unroll
  for (int m=0; m<6; m++){
    const float4* ap = (const float4*)(alpha + (((size_t)(i0+m))*Hh + j)*Hh);
    #pragma unroll
    for (int q=0; q<16; q++){
      float4 v = ap[q];
      areg[m][2*q+0] = pk16(v.x, v.y);
      areg[m][2*q+1] = pk16(v.z, v.w);
    }
  }
  // ---- alpha rows 6..7 -> LDS (private 256B block + 16B pad, imm offsets) ----
  #pragma unroll
  for (int mm=0; mm<2; mm++){
    const float4* ap = (const float4*)(alpha + (((size_t)(i0+6+mm))*Hh + j)*Hh);
    #pragma unroll
    for (int q=0; q<8; q++){
      float4 v0 = ap[2*q], v1 = ap[2*q+1];
      uint4 u;
      u.x = __builtin_bit_cast(unsigned, __builtin_amdgcn_cvt_pkrtz(v0.x, v0.y));
      u.y = __builtin_bit_cast(unsigned, __builtin_amdgcn_cvt_pkrtz(v0.z, v0.w));
      u.z = __builtin_bit_cast(unsigned, __builtin_amdgcn_cvt_pkrtz(v1.x, v1.y));
      u.w = __builtin_bit_cast(unsigned, __builtin_amdgcn_cvt_pkrtz(v1.z, v1.w));
      *(uint4*)(aL + (size_t)tid*272 + mm*128 + q*16) = u;
    }
  }
  __syncthreads();

  const int kzj = ((j >> 3) ^ j) & 7;   // read-side swizzle key (per-thread const)
  const int jc  = j >> 3;               // write-side chunk
  const int jo  = (j & 7) * 2;          // write-side byte offset in chunk

  float L = 0.f;

  for (int s=0; s<Tt; s++){
    const int cs = s & 1, ps = cs ^ 1;
    const int t  = (Tt-1) - s;

    float ipv = ipbuf[((size_t)b*Tt + t)*Hh + j];   // issued early, used late

    float acc[8];
    #pragma unroll
    for (int m=0;m<8;m++) acc[m] = 0.f;

    if (s){
      const char* zrow = zb[ps] + j*128;
      const char* arow = aL + (size_t)tid*272;
      #pragma unroll
      for (int h=0; h<2; h++){
        unsigned zz[16];
        #pragma unroll
        for (int c=0; c<4; c++){
          uint4 zq = *(const uint4*)(zrow + (((h*4+c) ^ kzj) << 4));
          zz[4*c+0]=zq.x; zz[4*c+1]=zq.y; zz[4*c+2]=zq.z; zz[4*c+3]=zq.w;
        }
        #pragma unroll
        for (int m=0; m<6; m++){
          #pragma unroll
          for (int p=0; p<16; p++)
            acc[m] = __builtin_amdgcn_fdot2(areg[m][16*h+p],
                       __builtin_bit_cast(half2_t, zz[p]), acc[m], false);
        }
        #pragma unroll
        for (int mm=0; mm<2; mm++){
          unsigned aa[16];
          #pragma unroll
          for (int c=0; c<4; c++){
            uint4 aq = *(const uint4*)(arow + mm*128 + h*64 + c*16);
            aa[4*c+0]=aq.x; aa[4*c+1]=aq.y; aa[4*c+2]=aq.z; aa[4*c+3]=aq.w;
          }
          #pragma unroll
          for (int p=0; p<16; p++)
            acc[6+mm] = __builtin_amdgcn_fdot2(__builtin_bit_cast(half2_t, aa[p]),
                           __builtin_bit_cast(half2_t, zz[p]), acc[6+mm], false);
        }
      }
      float e = __expf(ipv);
      #pragma unroll
      for (int m=0;m<8;m++) acc[m] *= e;        // W_s
    } else {
      float e = __expf(ipv);
      #pragma unroll
      for (int m=0;m<8;m++) acc[m] = e;         // W_0 = exp(ip), same for all i
    }

    // block max -> wred[cs]
    float vm = acc[0];
    #pragma unroll
    for (int m=1;m<8;m++) vm = fmaxf(vm, acc[m]);
    vm = wave_max64(vm);
    if (lane==0) wred[cs][w] = vm;

    // L_s = L_{s-1} + log(mu_{s-1})  (wred[ps] stable since prev step's 2nd barrier)
    if (s){
      float mu8 = wred[ps][0];
      #pragma unroll
      for (int q=1;q<8;q++) mu8 = fmaxf(mu8, wred[ps][q]);
      L += __logf(mu8);
    }
    if (tid==0) SL[(size_t)b*Tt + s] = L;

    // out staging: bf16(W) (emit kernel adds L and transposes), or direct fallback
    if (use_stage){
      unsigned pk4[4];
      #pragma unroll
      for (int q=0;q<4;q++)
        pk4[q] = (__float_as_uint(acc[2*q]) >> 16) | (__float_as_uint(acc[2*q+1]) & 0xFFFF0000u);
      uint4 o; o.x=pk4[0]; o.y=pk4[1]; o.z=pk4[2]; o.w=pk4[3];
      *(uint4*)(stage + ((size_t)s*Bb + b)*2048 + (size_t)j*32 + igrp*4) = o;
    } else {
      #pragma unroll
      for (int m=0;m<8;m++)
        out[(((size_t)s*Hh + (i0+m))*Hh + j)*Bb + b] = __logf(acc[m]) + L;
    }
    if (s == Tt-1){
      float4* ud = (float4*)(u511 + (size_t)b*4096 + (size_t)j*64 + i0);
      #pragma unroll
      for (int q=0;q<2;q++){
        float4 o; o.x=acc[4*q]; o.y=acc[4*q+1]; o.z=acc[4*q+2]; o.w=acc[4*q+3];
        ud[q] = o;
      }
    }

    __syncthreads();   // wred[cs] complete

    float mu   = wred[cs][0];
    #pragma unroll
    for (int q=1;q<8;q++) mu = fmaxf(mu, wred[cs][q]);
    float rinv = 1.0f / mu;
    {
      #pragma unroll
      for (int m=0;m<8;m++){
        int i = i0 + m;
        int ck = (jc ^ igrp ^ m) & 7;                         // chunk ^ key(i)
        _Float16 hv = (_Float16)fmaxf(acc[m]*rinv, 1e-7f);    // clamp: no all-zero rows
        *(short*)(zb[cs] + i*128 + (ck<<4) + jo) = __builtin_bit_cast(short, hv);
      }
    }
    __syncthreads();   // zb[cs] ready for next step
  }
}

// transpose + log: stage[s][b][j][i] bf16 -> out[s][i][j][b] f32 (= log(W)+L)
__global__ __launch_bounds__(256) void sohmm_emit(
    const unsigned short* __restrict__ stage, const float* __restrict__ SL,
    float* __restrict__ out)
{
  const int s  = blockIdx.x >> 3;
  const int jb = blockIdx.x & 7;
  const int tid = threadIdx.x;

  __shared__ unsigned short T[32*514];
  __shared__ float Sl[32];

  if (tid < 32) Sl[tid] = SL[(size_t)tid*Tt + s];

  #pragma unroll 4
  for (int bb=0; bb<32; bb++){
    ushort2 v = ((const ushort2*)(stage + ((size_t)s*Bb + bb)*4096 + (size_t)jb*512))[tid];
    *(ushort2*)(&T[bb*514 + tid*2]) = v;
  }
  __syncthreads();

  const int bch = tid & 31;
  const int pg  = tid >> 5;
  #pragma unroll 4
  for (int r=0; r<64; r++){
    int p  = r*8 + pg;
    int jr = p >> 6;
    int i  = p & 63;
    unsigned short h = T[bch*514 + jr*64 + i];
    float u = __uint_as_float(((unsigned)h) << 16);
    out[(((size_t)s*Hh + i)*Hh + (jb*8 + jr))*Bb + bch] = __logf(u) + Sl[bch];
  }
}

__global__ __launch_bounds__(256) void sohmm_final(
    const float* __restrict__ gamma, const float* __restrict__ u511,
    const float* __restrict__ SL, float* __restrict__ out)
{
  const int b = blockIdx.x, tid = threadIdx.x;
  const int w = tid>>6, lane = tid&63;
  __shared__ float red[4], red2[4];

  float gm = -3.4e38f;
  #pragma unroll
  for (int q=0;q<16;q++) gm = fmaxf(gm, gamma[q*256+tid]);
  gm = wave_max64(gm);
  if (lane==0) red[w] = gm;
  __syncthreads();
  gm = fmaxf(fmaxf(red[0],red[1]), fmaxf(red[2],red[3]));
  __syncthreads();

  float se=0.f, dot=0.f;
  #pragma unroll
  for (int q=0;q<16;q++){
    int idx = q*256+tid;             // i*64+j
    int ii = idx>>6, jj = idx&63;
    float gq = __expf(gamma[idx]-gm);
    se  += gq;
    dot += gq * u511[(size_t)b*4096 + (size_t)jj*64 + ii];
  }
  #pragma unroll
  for (int off=32; off; off>>=1){
    se  += __shfl_xor(se,  off, 64);
    dot += __shfl_xor(dot, off, 64);
  }
  if (lane==0){ red[w]=se; red2[w]=dot; }
  __syncthreads();
  if (tid==0){
    float ses  = red[0]+red[1]+red[2]+red[3];
    float dots = red2[0]+red2[1]+red2[2]+red2[3];
    out[(size_t)Tt*Hh*Hh*Bb + b] = __logf(dots/ses) + SL[(size_t)b*Tt + (Tt-1)];
  }
}

extern "C" void kernel_launch(void* const* d_in, const int* in_sizes, int n_in,
                              void* d_out, int out_size, void* d_ws, size_t ws_size,
                              hipStream_t stream)
{
  (void)in_sizes; (void)n_in; (void)out_size;
  const float* alpha = (const float*)d_in[0];
  const float* beta  = (const float*)d_in[1];
  const float* gamma = (const float*)d_in[2];
  const int*   ids   = (const int*)d_in[3];
  float* out = (float*)d_out;
  char*  ws  = (char*)d_ws;

  float*          ipbuf = (float*)(ws + IP_OFF);
  float*          SLp   = (float*)(ws + SL_OFF);
  float*          u511p = (float*)(ws + U511_OFF);
  unsigned int*   stage = (unsigned int*)(ws + STAGE_OFF);

  const int use_stage = (ws_size >= STAGE_OFF + STAGE_SZ) ? 1 : 0;

  hipLaunchKernelGGL(sohmm_ipfill, dim3(Bb*128), dim3(256), 0, stream, beta, ids, ipbuf);
  hipLaunchKernelGGL(sohmm_scan, dim3(Bb), dim3(512), 0, stream,
                     alpha, ipbuf, out, SLp, u511p, stage, use_stage);
  if (use_stage){
    hipLaunchKernelGGL(sohmm_emit, dim3(Tt*8), dim3(256), 0, stream,
                       (const unsigned short*)stage, SLp, out);
  }
  hipLaunchKernelGGL(sohmm_final, dim3(Bb), dim3(256), 0, stream,
                     gamma, u511p, SLp, out);
}

// Round 14
// 1170.945 us; speedup vs baseline: 1.5490x; 1.0390x over previous
//
#include <hip/hip_runtime.h>
#include <cstdint>
#include <cstddef>

#define Hh 64
#define Vv 32000
#define Bb 32
#define Tt 512

typedef _Float16 half2_t __attribute__((ext_vector_type(2)));

// ---- ws layout (bytes) ----
#define IP_OFF    0ull
#define IP_SZ     ((size_t)Bb*Tt*Hh*4)          // 4 MB   ip[b][t][j]
#define SL_OFF    (IP_OFF + IP_SZ)
#define SL_SZ     ((size_t)Bb*Tt*4)             // 64 KB  logC[b][s]
#define DM_OFF    (SL_OFF + SL_SZ)
#define DM_SZ     ((size_t)Bb*Tt*4)             // 64 KB  delta[b][t] = max_j ip
#define U511_OFF  (DM_OFF + DM_SZ)
#define U511_SZ   ((size_t)Bb*Hh*Hh*4)          // 512 KB y511[b][j][i] f32
#define STAGE_OFF (U511_OFF + U511_SZ)
#define STAGE_SZ  ((size_t)Tt*Bb*Hh*Hh*2)       // 128 MB stage[s][b][j][i] bf16

__device__ __forceinline__ float wave_max64(float v){
  #pragma unroll
  for (int off=32; off; off>>=1) v = fmaxf(v, __shfl_xor(v, off, 64));
  return v;
}

__device__ __forceinline__ half2_t pk16(float x, float y){
  return __builtin_bit_cast(half2_t, __builtin_amdgcn_cvt_pkrtz(x, y));
}

// emissions + per-t max: ip[b][t][j] = beta[j][ids[b][t]]; dmax[b][t] = max_j
__global__ __launch_bounds__(256) void sohmm_ipfill(
    const float* __restrict__ beta, const int* __restrict__ ids,
    float* __restrict__ ipbuf, float* __restrict__ dmax)
{
  const int bid = blockIdx.x;
  const int b = bid >> 7, tq = bid & 127;
  const int t = tq*4 + (threadIdx.x >> 6);
  const int j = threadIdx.x & 63;
  const int id = ids[b*Tt + t];
  float ip = beta[(size_t)j*Vv + id];
  ipbuf[((size_t)b*Tt + t)*Hh + j] = ip;
  float m = wave_max64(ip);
  if (j == 0) dmax[b*Tt + t] = m;
}

// One WG (512 threads, 8 waves, 2 waves/SIMD) per chain. ONE barrier per step.
// thread (j = tid>>3, igrp = tid&7) owns outputs (i = igrp*8+m, j), m=0..7.
// alpha f16: rows 0..5 in regs, rows 6..7 in LDS. zb: f16, chunk-XOR swizzled.
// Scale scheme: y_s = u_s / C_s with C_s = C_{s-1} * M_{s-1} * e^{delta_s};
//   y_s = (sum_k alpha*y_{s-1}) * e^{ip - delta_s} / M_{s-1}  <= 1 always.
//   M = measured block max of y (wred), logC tracked redundantly per thread.
__global__ __launch_bounds__(512)
void sohmm_scan(
    const float* __restrict__ alpha, const float* __restrict__ ipbuf,
    const float* __restrict__ dmax,
    float* __restrict__ out, float* __restrict__ SL,
    float* __restrict__ u511, unsigned int* __restrict__ stage, int use_stage)
{
  const int b    = blockIdx.x;
  const int tid  = threadIdx.x;
  const int j    = tid >> 3;     // 0..63
  const int igrp = tid & 7;      // 0..7
  const int w    = tid >> 6;     // wave 0..7
  const int lane = tid & 63;
  const int i0   = igrp * 8;

  __shared__ char zb[2][64*128];        // 16,384 B   state y f16, swizzled chunks
  __shared__ char aL[512*272];          // 139,264 B  2 alpha rows per thread
  __shared__ float wred[2][8];          // wave maxes, double-buffered

  // ---- alpha rows 0..5 -> registers (f16) ----
  half2_t areg[6][32];
  #pragma unroll
  for (int m=0; m<6; m++){
    const float4* ap = (const float4*)(alpha + (((size_t)(i0+m))*Hh + j)*Hh);
    #pragma unroll
    for (int q=0; q<16; q++){
      float4 v = ap[q];
      areg[m][2*q+0] = pk16(v.x, v.y);
      areg[m][2*q+1] = pk16(v.z, v.w);
    }
  }
  // ---- alpha rows 6..7 -> LDS (private 256B block + 16B pad, imm offsets) ----
  #pragma unroll
  for (int mm=0; mm<2; mm++){
    const float4* ap = (const float4*)(alpha + (((size_t)(i0+6+mm))*Hh + j)*Hh);
    #pragma unroll
    for (int q=0; q<8; q++){
      float4 v0 = ap[2*q], v1 = ap[2*q+1];
      uint4 u;
      u.x = __builtin_bit_cast(unsigned, __builtin_amdgcn_cvt_pkrtz(v0.x, v0.y));
      u.y = __builtin_bit_cast(unsigned, __builtin_amdgcn_cvt_pkrtz(v0.z, v0.w));
      u.z = __builtin_bit_cast(unsigned, __builtin_amdgcn_cvt_pkrtz(v1.x, v1.y));
      u.w = __builtin_bit_cast(unsigned, __builtin_amdgcn_cvt_pkrtz(v1.z, v1.w));
      *(uint4*)(aL + (size_t)tid*272 + mm*128 + q*16) = u;
    }
  }
  __syncthreads();

  const int kzj = ((j >> 3) ^ j) & 7;   // read-side swizzle key
  const int jc  = j >> 3;               // write-side chunk
  const int jo  = (j & 7) * 2;          // write-side byte offset in chunk

  float logC = 0.f;

  for (int s=0; s<Tt; s++){
    const int cs = s & 1, ps = cs ^ 1;
    const int t  = (Tt-1) - s;

    float ipv = ipbuf[((size_t)b*Tt + t)*Hh + j];   // hoisted loads
    float dmv = dmax[b*Tt + t];

    float y[8];

    if (s){
      // M_{s-1}: wred[ps] complete since last barrier; 2x b128 read
      uint4 w0 = *(const uint4*)(&wred[ps][0]);
      uint4 w1 = *(const uint4*)(&wred[ps][4]);
      float Mprev = fmaxf(
        fmaxf(fmaxf(__uint_as_float(w0.x),__uint_as_float(w0.y)),
              fmaxf(__uint_as_float(w0.z),__uint_as_float(w0.w))),
        fmaxf(fmaxf(__uint_as_float(w1.x),__uint_as_float(w1.y)),
              fmaxf(__uint_as_float(w1.z),__uint_as_float(w1.w))));

      float acc[8];
      #pragma unroll
      for (int m=0;m<8;m++) acc[m] = 0.f;

      const char* zrow = zb[ps] + j*128;
      const char* arow = aL + (size_t)tid*272;
      #pragma unroll
      for (int h=0; h<2; h++){
        unsigned zz[16];
        #pragma unroll
        for (int c=0; c<4; c++){
          uint4 zq = *(const uint4*)(zrow + (((h*4+c) ^ kzj) << 4));
          zz[4*c+0]=zq.x; zz[4*c+1]=zq.y; zz[4*c+2]=zq.z; zz[4*c+3]=zq.w;
        }
        #pragma unroll
        for (int m=0; m<6; m++){
          #pragma unroll
          for (int p=0; p<16; p++)
            acc[m] = __builtin_amdgcn_fdot2(areg[m][16*h+p],
                       __builtin_bit_cast(half2_t, zz[p]), acc[m], false);
        }
        #pragma unroll
        for (int mm=0; mm<2; mm++){
          unsigned aa[16];
          #pragma unroll
          for (int c=0; c<4; c++){
            uint4 aq = *(const uint4*)(arow + mm*128 + h*64 + c*16);
            aa[4*c+0]=aq.x; aa[4*c+1]=aq.y; aa[4*c+2]=aq.z; aa[4*c+3]=aq.w;
          }
          #pragma unroll
          for (int p=0; p<16; p++)
            acc[6+mm] = __builtin_amdgcn_fdot2(__builtin_bit_cast(half2_t, aa[p]),
                           __builtin_bit_cast(half2_t, zz[p]), acc[6+mm], false);
        }
      }
      float scale = __expf(ipv - dmv) / Mprev;
      #pragma unroll
      for (int m=0;m<8;m++) y[m] = acc[m] * scale;
      logC += __logf(Mprev) + dmv;
    } else {
      float e = __expf(ipv - dmv);
      #pragma unroll
      for (int m=0;m<8;m++) y[m] = e;        // y_0, same for all i
      logC = dmv;
    }

    // wave max -> wred[cs] (pre-barrier; consumed next step post-barrier)
    float vm = y[0];
    #pragma unroll
    for (int m=1;m<8;m++) vm = fmaxf(vm, y[m]);
    vm = wave_max64(vm);
    if (lane==0) wred[cs][w] = vm;

    if (tid==0) SL[(size_t)b*Tt + s] = logC;

    // out staging: bf16(y) (emit adds logC and transposes), or direct fallback
    if (use_stage){
      unsigned pk4[4];
      #pragma unroll
      for (int q=0;q<4;q++)
        pk4[q] = (__float_as_uint(y[2*q]) >> 16) | (__float_as_uint(y[2*q+1]) & 0xFFFF0000u);
      uint4 o; o.x=pk4[0]; o.y=pk4[1]; o.z=pk4[2]; o.w=pk4[3];
      *(uint4*)(stage + ((size_t)s*Bb + b)*2048 + (size_t)j*32 + igrp*4) = o;
    } else {
      #pragma unroll
      for (int m=0;m<8;m++)
        out[(((size_t)s*Hh + (i0+m))*Hh + j)*Bb + b] = __logf(y[m]) + logC;
    }
    if (s == Tt-1){
      float4* ud = (float4*)(u511 + (size_t)b*4096 + (size_t)j*64 + i0);
      #pragma unroll
      for (int q=0;q<2;q++){
        float4 o; o.x=y[4*q]; o.y=y[4*q+1]; o.z=y[4*q+2]; o.w=y[4*q+3];
        ud[q] = o;
      }
    }

    // zb[cs] write (f16, clamped against all-zero rows)
    {
      #pragma unroll
      for (int m=0;m<8;m++){
        int i = i0 + m;
        int ck = (jc ^ igrp ^ m) & 7;
        _Float16 hv = (_Float16)fmaxf(y[m], 1e-7f);
        *(short*)(zb[cs] + i*128 + (ck<<4) + jo) = __builtin_bit_cast(short, hv);
      }
    }

    __syncthreads();   // single barrier: publishes zb[cs] + wred[cs]
  }
}

// transpose + log: stage[s][b][j][i] bf16 -> out[s][i][j][b] f32 (= log(y)+logC)
__global__ __launch_bounds__(256) void sohmm_emit(
    const unsigned short* __restrict__ stage, const float* __restrict__ SL,
    float* __restrict__ out)
{
  const int s  = blockIdx.x >> 3;
  const int jb = blockIdx.x & 7;
  const int tid = threadIdx.x;

  __shared__ unsigned short T[32*514];
  __shared__ float Sl[32];

  if (tid < 32) Sl[tid] = SL[(size_t)tid*Tt + s];

  #pragma unroll 4
  for (int bb=0; bb<32; bb++){
    ushort2 v = ((const ushort2*)(stage + ((size_t)s*Bb + bb)*4096 + (size_t)jb*512))[tid];
    *(ushort2*)(&T[bb*514 + tid*2]) = v;
  }
  __syncthreads();

  const int bch = tid & 31;
  const int pg  = tid >> 5;
  #pragma unroll 4
  for (int r=0; r<64; r++){
    int p  = r*8 + pg;
    int jr = p >> 6;
    int i  = p & 63;
    unsigned short h = T[bch*514 + jr*64 + i];
    float u = __uint_as_float(((unsigned)h) << 16);
    out[(((size_t)s*Hh + i)*Hh + (jb*8 + jr))*Bb + bch] = __logf(u) + Sl[bch];
  }
}

__global__ __launch_bounds__(256) void sohmm_final(
    const float* __restrict__ gamma, const float* __restrict__ u511,
    const float* __restrict__ SL, float* __restrict__ out)
{
  const int b = blockIdx.x, tid = threadIdx.x;
  const int w = tid>>6, lane = tid&63;
  __shared__ float red[4], red2[4];

  float gm = -3.4e38f;
  #pragma unroll
  for (int q=0;q<16;q++) gm = fmaxf(gm, gamma[q*256+tid]);
  gm = wave_max64(gm);
  if (lane==0) red[w] = gm;
  __syncthreads();
  gm = fmaxf(fmaxf(red[0],red[1]), fmaxf(red[2],red[3]));
  __syncthreads();

  float se=0.f, dot=0.f;
  #pragma unroll
  for (int q=0;q<16;q++){
    int idx = q*256+tid;             // i*64+j
    int ii = idx>>6, jj = idx&63;
    float gq = __expf(gamma[idx]-gm);
    se  += gq;
    dot += gq * u511[(size_t)b*4096 + (size_t)jj*64 + ii];
  }
  #pragma unroll
  for (int off=32; off; off>>=1){
    se  += __shfl_xor(se,  off, 64);
    dot += __shfl_xor(dot, off, 64);
  }
  if (lane==0){ red[w]=se; red2[w]=dot; }
  __syncthreads();
  if (tid==0){
    float ses  = red[0]+red[1]+red[2]+red[3];
    float dots = red2[0]+red2[1]+red2[2]+red2[3];
    out[(size_t)Tt*Hh*Hh*Bb + b] = __logf(dots/ses) + SL[(size_t)b*Tt + (Tt-1)];
  }
}

extern "C" void kernel_launch(void* const* d_in, const int* in_sizes, int n_in,
                              void* d_out, int out_size, void* d_ws, size_t ws_size,
                              hipStream_t stream)
{
  (void)in_sizes; (void)n_in; (void)out_size;
  const float* alpha = (const float*)d_in[0];
  const float* beta  = (const float*)d_in[1];
  const float* gamma = (const float*)d_in[2];
  const int*   ids   = (const int*)d_in[3];
  float* out = (float*)d_out;
  char*  ws  = (char*)d_ws;

  float*          ipbuf = (float*)(ws + IP_OFF);
  float*          SLp   = (float*)(ws + SL_OFF);
  float*          dmaxp = (float*)(ws + DM_OFF);
  float*          u511p = (float*)(ws + U511_OFF);
  unsigned int*   stage = (unsigned int*)(ws + STAGE_OFF);

  const int use_stage = (ws_size >= STAGE_OFF + STAGE_SZ) ? 1 : 0;

  hipLaunchKernelGGL(sohmm_ipfill, dim3(Bb*128), dim3(256), 0, stream,
                     beta, ids, ipbuf, dmaxp);
  hipLaunchKernelGGL(sohmm_scan, dim3(Bb), dim3(512), 0, stream,
                     alpha, ipbuf, dmaxp, out, SLp, u511p, stage, use_stage);
  if (use_stage){
    hipLaunchKernelGGL(sohmm_emit, dim3(Tt*8), dim3(256), 0, stream,
                       (const unsigned short*)stage, SLp, out);
  }
  hipLaunchKernelGGL(sohmm_final, dim3(Bb), dim3(256), 0, stream,
                     gamma, u511p, SLp, out);
}

// Round 15
// 1073.516 us; speedup vs baseline: 1.6895x; 1.0908x over previous
//
#include <hip/hip_runtime.h>
#include <cstdint>
#include <cstddef>

#define Hh 64
#define Vv 32000
#define Bb 32
#define Tt 512

typedef _Float16 half2_t __attribute__((ext_vector_type(2)));

// ---- ws layout (bytes) ----
#define IP_OFF    0ull
#define IP_SZ     ((size_t)Bb*Tt*Hh*4)          // 4 MB   ip[b][t][j]
#define SL_OFF    (IP_OFF + IP_SZ)
#define SL_SZ     ((size_t)Bb*Tt*4)             // 64 KB  logC[b][s]
#define DM_OFF    (SL_OFF + SL_SZ)
#define DM_SZ     ((size_t)Bb*Tt*4)             // 64 KB  delta[b][t]
#define U511_OFF  (DM_OFF + DM_SZ)
#define U511_SZ   ((size_t)Bb*Hh*Hh*4)          // 512 KB y511[b][j][i] f32
#define STAGE_OFF (U511_OFF + U511_SZ)
#define STAGE_SZ  ((size_t)Tt*Bb*Hh*Hh*2)       // 128 MB stage[s][b][j][i] bf16

__device__ __forceinline__ float wave_max64(float v){
  #pragma unroll
  for (int off=32; off; off>>=1) v = fmaxf(v, __shfl_xor(v, off, 64));
  return v;
}

__device__ __forceinline__ half2_t pk16(float x, float y){
  return __builtin_bit_cast(half2_t, __builtin_amdgcn_cvt_pkrtz(x, y));
}

// DPP-based wave max; full-wave max valid in lanes 48..63 (we use lane 63).
// bound_ctrl=false + old=0 is safe: y > 0 always, fmax(v,0)=v.
#define DPP_MAXSTEP(v, CTRL) \
  v = fmaxf(v, __int_as_float(__builtin_amdgcn_update_dpp(0, __float_as_int(v), CTRL, 0xF, 0xF, false)))

__device__ __forceinline__ float wave_max_dpp63(float v){
  DPP_MAXSTEP(v, 0xB1);   // quad_perm(1,0,3,2)  ~xor1
  DPP_MAXSTEP(v, 0x4E);   // quad_perm(2,3,0,1)  ~xor2
  DPP_MAXSTEP(v, 0x141);  // row_half_mirror
  DPP_MAXSTEP(v, 0x140);  // row_mirror
  DPP_MAXSTEP(v, 0x142);  // row_bcast15
  DPP_MAXSTEP(v, 0x143);  // row_bcast31
  return v;
}

// emissions + per-t max
__global__ __launch_bounds__(256) void sohmm_ipfill(
    const float* __restrict__ beta, const int* __restrict__ ids,
    float* __restrict__ ipbuf, float* __restrict__ dmax)
{
  const int bid = blockIdx.x;
  const int b = bid >> 7, tq = bid & 127;
  const int t = tq*4 + (threadIdx.x >> 6);
  const int j = threadIdx.x & 63;
  const int id = ids[b*Tt + t];
  float ip = beta[(size_t)j*Vv + id];
  ipbuf[((size_t)b*Tt + t)*Hh + j] = ip;
  float m = wave_max64(ip);
  if (j == 0) dmax[b*Tt + t] = m;
}

// One WG (512 threads, 8 waves) per chain. ONE barrier per step, 2x-unrolled
// with compile-time parity so every LDS access is base-reg + immediate.
__global__ __launch_bounds__(512)
void sohmm_scan(
    const float* __restrict__ alpha, const float* __restrict__ ipbuf,
    const float* __restrict__ dmax,
    float* __restrict__ out, float* __restrict__ SL,
    float* __restrict__ u511, unsigned int* __restrict__ stage, int use_stage)
{
  const int b    = blockIdx.x;
  const int tid  = threadIdx.x;
  const int j    = tid >> 3;     // 0..63
  const int igrp = tid & 7;      // 0..7
  const int w    = tid >> 6;     // wave 0..7
  const int lane = tid & 63;
  const int i0   = igrp * 8;

  __shared__ char zb[2][64*128];              // state y f16, chunk-XOR swizzled
  __shared__ char aL[512*272];                // 2 alpha rows per thread
  __shared__ __align__(16) float wred[2][8];  // wave maxes, double-buffered

  // ---- alpha rows 0..5 -> registers (f16) ----
  half2_t areg[6][32];
  #pragma unroll
  for (int m=0; m<6; m++){
    const float4* ap = (const float4*)(alpha + (((size_t)(i0+m))*Hh + j)*Hh);
    #pragma unroll
    for (int q=0; q<16; q++){
      float4 v = ap[q];
      areg[m][2*q+0] = pk16(v.x, v.y);
      areg[m][2*q+1] = pk16(v.z, v.w);
    }
  }
  // ---- alpha rows 6..7 -> LDS ----
  #pragma unroll
  for (int mm=0; mm<2; mm++){
    const float4* ap = (const float4*)(alpha + (((size_t)(i0+6+mm))*Hh + j)*Hh);
    #pragma unroll
    for (int q=0; q<8; q++){
      float4 v0 = ap[2*q], v1 = ap[2*q+1];
      uint4 u;
      u.x = __builtin_bit_cast(unsigned, __builtin_amdgcn_cvt_pkrtz(v0.x, v0.y));
      u.y = __builtin_bit_cast(unsigned, __builtin_amdgcn_cvt_pkrtz(v0.z, v0.w));
      u.z = __builtin_bit_cast(unsigned, __builtin_amdgcn_cvt_pkrtz(v1.x, v1.y));
      u.w = __builtin_bit_cast(unsigned, __builtin_amdgcn_cvt_pkrtz(v1.z, v1.w));
      *(uint4*)(aL + (size_t)tid*272 + mm*128 + q*16) = u;
    }
  }
  __syncthreads();

  const int kzj = ((j >> 3) ^ j) & 7;
  const int jc  = j >> 3;
  const int jo  = (j & 7) * 2;

  // precomputed parity-0 addresses; parity 1 = +8192 immediate
  const char* zr0[8];
  char*       zw0[8];
  #pragma unroll
  for (int c=0;c<8;c++) zr0[c] = zb[0] + j*128 + ((c ^ kzj) << 4);
  #pragma unroll
  for (int m=0;m<8;m++) zw0[m] = zb[0] + (i0+m)*128 + (((jc ^ igrp ^ m) & 7) << 4) + jo;
  const char* arow = aL + (size_t)tid*272;

  const float* ipp = ipbuf + (size_t)b*Tt*Hh + (size_t)(Tt-1)*Hh + j;
  const float* dmp = dmax + b*Tt + (Tt-1);
  float*       slp = SL + (size_t)b*Tt;
  unsigned*    stg = stage + (size_t)b*2048 + (size_t)j*32 + igrp*4;
  float*       outp = out + (((size_t)i0)*Hh + j)*Bb + b;   // fallback path

  float y[8];
  float logC;

  // ---- s = 0 ----
  {
    float ipv = *ipp; ipp -= Hh;
    float dmv = *dmp; dmp -= 1;
    float e = __expf(ipv - dmv);
    #pragma unroll
    for (int m=0;m<8;m++) y[m] = e;
    logC = dmv;
    float vm = wave_max_dpp63(e);
    if (lane==63) wred[0][w] = vm;
    if (tid==0) slp[0] = logC;
    if (use_stage){
      unsigned pk4[4];
      #pragma unroll
      for (int q=0;q<4;q++)
        pk4[q] = __builtin_amdgcn_perm(__float_as_uint(y[2*q+1]), __float_as_uint(y[2*q]), 0x07060302);
      uint4 o; o.x=pk4[0]; o.y=pk4[1]; o.z=pk4[2]; o.w=pk4[3];
      *(uint4*)stg = o;
    } else {
      #pragma unroll
      for (int m=0;m<8;m++) outp[(size_t)m*Hh*Bb] = __logf(y[m]) + logC;
    }
    stg += Bb*2048; outp += (size_t)Hh*Hh*Bb;
    #pragma unroll
    for (int m=0;m<8;m++){
      _Float16 hv = (_Float16)fmaxf(y[m], 1e-7f);
      *(short*)(zw0[m]) = __builtin_bit_cast(short, hv);
    }
    __syncthreads();
  }

#define STEP(CS) { \
    float ipv = *ipp; ipp -= Hh; \
    float dmv = *dmp; dmp -= 1; \
    slp += 1; \
    uint4 q0 = *(const uint4*)(&wred[CS^1][0]); \
    uint4 q1 = *(const uint4*)(&wred[CS^1][4]); \
    float Mp = fmaxf( \
      fmaxf(fmaxf(__uint_as_float(q0.x),__uint_as_float(q0.y)), \
            fmaxf(__uint_as_float(q0.z),__uint_as_float(q0.w))), \
      fmaxf(fmaxf(__uint_as_float(q1.x),__uint_as_float(q1.y)), \
            fmaxf(__uint_as_float(q1.z),__uint_as_float(q1.w)))); \
    float acc[8]; \
    _Pragma("unroll") for (int m=0;m<8;m++) acc[m] = 0.f; \
    _Pragma("unroll") \
    for (int h=0; h<2; h++){ \
      unsigned zz[16]; \
      _Pragma("unroll") \
      for (int c=0; c<4; c++){ \
        uint4 zq = *(const uint4*)(zr0[h*4+c] + (CS^1)*8192); \
        zz[4*c+0]=zq.x; zz[4*c+1]=zq.y; zz[4*c+2]=zq.z; zz[4*c+3]=zq.w; \
      } \
      _Pragma("unroll") \
      for (int m=0; m<6; m++){ \
        _Pragma("unroll") \
        for (int p=0; p<16; p++) \
          acc[m] = __builtin_amdgcn_fdot2(areg[m][16*h+p], \
                     __builtin_bit_cast(half2_t, zz[p]), acc[m], false); \
      } \
      _Pragma("unroll") \
      for (int mm=0; mm<2; mm++){ \
        unsigned aa[16]; \
        _Pragma("unroll") \
        for (int c=0; c<4; c++){ \
          uint4 aq = *(const uint4*)(arow + mm*128 + h*64 + c*16); \
          aa[4*c+0]=aq.x; aa[4*c+1]=aq.y; aa[4*c+2]=aq.z; aa[4*c+3]=aq.w; \
        } \
        _Pragma("unroll") \
        for (int p=0; p<16; p++) \
          acc[6+mm] = __builtin_amdgcn_fdot2(__builtin_bit_cast(half2_t, aa[p]), \
                         __builtin_bit_cast(half2_t, zz[p]), acc[6+mm], false); \
      } \
    } \
    float scale = __expf(ipv - dmv) * __builtin_amdgcn_rcpf(Mp); \
    _Pragma("unroll") for (int m=0;m<8;m++) y[m] = acc[m]*scale; \
    logC += __logf(Mp) + dmv; \
    float vm = fmaxf(fmaxf(fmaxf(y[0],y[1]),fmaxf(y[2],y[3])), \
                     fmaxf(fmaxf(y[4],y[5]),fmaxf(y[6],y[7]))); \
    vm = wave_max_dpp63(vm); \
    if (lane==63) wred[CS][w] = vm; \
    if (tid==0) *slp = logC; \
    if (use_stage){ \
      unsigned pk4[4]; \
      _Pragma("unroll") \
      for (int q=0;q<4;q++) \
        pk4[q] = __builtin_amdgcn_perm(__float_as_uint(y[2*q+1]), __float_as_uint(y[2*q]), 0x07060302); \
      uint4 o; o.x=pk4[0]; o.y=pk4[1]; o.z=pk4[2]; o.w=pk4[3]; \
      *(uint4*)stg = o; \
    } else { \
      _Pragma("unroll") \
      for (int m=0;m<8;m++) outp[(size_t)m*Hh*Bb] = __logf(y[m]) + logC; \
    } \
    stg += Bb*2048; outp += (size_t)Hh*Hh*Bb; \
    _Pragma("unroll") \
    for (int m=0;m<8;m++){ \
      _Float16 hv = (_Float16)fmaxf(y[m], 1e-7f); \
      *(short*)(zw0[m] + (CS)*8192) = __builtin_bit_cast(short, hv); \
    } \
    __syncthreads(); \
  }

  // steps 1..510 as 255 compile-time-parity pairs, tail s=511
  for (int sp=0; sp<255; sp++){
    STEP(1)
    STEP(0)
  }
  STEP(1)
#undef STEP

  // y holds y_511
  {
    float4* ud = (float4*)(u511 + (size_t)b*4096 + (size_t)j*64 + i0);
    #pragma unroll
    for (int q=0;q<2;q++){
      float4 o; o.x=y[4*q]; o.y=y[4*q+1]; o.z=y[4*q+2]; o.w=y[4*q+3];
      ud[q] = o;
    }
  }
}

// transpose + log: stage[s][b][j][i] bf16 -> out[s][i][j][b] f32
__global__ __launch_bounds__(256) void sohmm_emit(
    const unsigned short* __restrict__ stage, const float* __restrict__ SL,
    float* __restrict__ out)
{
  const int s  = blockIdx.x >> 3;
  const int jb = blockIdx.x & 7;
  const int tid = threadIdx.x;

  __shared__ unsigned short T[32*514];
  __shared__ float Sl[32];

  if (tid < 32) Sl[tid] = SL[(size_t)tid*Tt + s];

  #pragma unroll 4
  for (int bb=0; bb<32; bb++){
    ushort2 v = ((const ushort2*)(stage + ((size_t)s*Bb + bb)*4096 + (size_t)jb*512))[tid];
    *(ushort2*)(&T[bb*514 + tid*2]) = v;
  }
  __syncthreads();

  const int bch = tid & 31;
  const int pg  = tid >> 5;
  #pragma unroll 4
  for (int r=0; r<64; r++){
    int p  = r*8 + pg;
    int jr = p >> 6;
    int i  = p & 63;
    unsigned short h = T[bch*514 + jr*64 + i];
    float u = __uint_as_float(((unsigned)h) << 16);
    out[(((size_t)s*Hh + i)*Hh + (jb*8 + jr))*Bb + bch] = __logf(u) + Sl[bch];
  }
}

__global__ __launch_bounds__(256) void sohmm_final(
    const float* __restrict__ gamma, const float* __restrict__ u511,
    const float* __restrict__ SL, float* __restrict__ out)
{
  const int b = blockIdx.x, tid = threadIdx.x;
  const int w = tid>>6, lane = tid&63;
  __shared__ float red[4], red2[4];

  float gm = -3.4e38f;
  #pragma unroll
  for (int q=0;q<16;q++) gm = fmaxf(gm, gamma[q*256+tid]);
  gm = wave_max64(gm);
  if (lane==0) red[w] = gm;
  __syncthreads();
  gm = fmaxf(fmaxf(red[0],red[1]), fmaxf(red[2],red[3]));
  __syncthreads();

  float se=0.f, dot=0.f;
  #pragma unroll
  for (int q=0;q<16;q++){
    int idx = q*256+tid;             // i*64+j
    int ii = idx>>6, jj = idx&63;
    float gq = __expf(gamma[idx]-gm);
    se  += gq;
    dot += gq * u511[(size_t)b*4096 + (size_t)jj*64 + ii];
  }
  #pragma unroll
  for (int off=32; off; off>>=1){
    se  += __shfl_xor(se,  off, 64);
    dot += __shfl_xor(dot, off, 64);
  }
  if (lane==0){ red[w]=se; red2[w]=dot; }
  __syncthreads();
  if (tid==0){
    float ses  = red[0]+red[1]+red[2]+red[3];
    float dots = red2[0]+red2[1]+red2[2]+red2[3];
    out[(size_t)Tt*Hh*Hh*Bb + b] = __logf(dots/ses) + SL[(size_t)b*Tt + (Tt-1)];
  }
}

extern "C" void kernel_launch(void* const* d_in, const int* in_sizes, int n_in,
                              void* d_out, int out_size, void* d_ws, size_t ws_size,
                              hipStream_t stream)
{
  (void)in_sizes; (void)n_in; (void)out_size;
  const float* alpha = (const float*)d_in[0];
  const float* beta  = (const float*)d_in[1];
  const float* gamma = (const float*)d_in[2];
  const int*   ids   = (const int*)d_in[3];
  float* out = (float*)d_out;
  char*  ws  = (char*)d_ws;

  float*          ipbuf = (float*)(ws + IP_OFF);
  float*          SLp   = (float*)(ws + SL_OFF);
  float*          dmaxp = (float*)(ws + DM_OFF);
  float*          u511p = (float*)(ws + U511_OFF);
  unsigned int*   stage = (unsigned int*)(ws + STAGE_OFF);

  const int use_stage = (ws_size >= STAGE_OFF + STAGE_SZ) ? 1 : 0;

  hipLaunchKernelGGL(sohmm_ipfill, dim3(Bb*128), dim3(256), 0, stream,
                     beta, ids, ipbuf, dmaxp);
  hipLaunchKernelGGL(sohmm_scan, dim3(Bb), dim3(512), 0, stream,
                     alpha, ipbuf, dmaxp, out, SLp, u511p, stage, use_stage);
  if (use_stage){
    hipLaunchKernelGGL(sohmm_emit, dim3(Tt*8), dim3(256), 0, stream,
                       (const unsigned short*)stage, SLp, out);
  }
  hipLaunchKernelGGL(sohmm_final, dim3(Bb), dim3(256), 0, stream,
                     gamma, u511p, SLp, out);
}